// Round 10
// baseline (948.549 us; speedup 1.0000x reference)
//
#include <hip/hip_runtime.h>
#include <math.h>

#define TSEQ 2048
#define EMB  1024
#define NH   16
#define HD   64
#define NB   2
#define L2E  1.4426950408889634f

#if defined(__has_builtin)
#if __has_builtin(__builtin_amdgcn_exp2f)
#define EXP2(x) __builtin_amdgcn_exp2f(x)
#else
#define EXP2(x) exp2f(x)
#endif
#else
#define EXP2(x) exp2f(x)
#endif

typedef unsigned short u16;
typedef unsigned int   u32;
typedef __attribute__((ext_vector_type(8))) short short8v;  // 8 bf16
typedef __attribute__((ext_vector_type(4))) float f32x4;

#define MFMA16(a,b,c) __builtin_amdgcn_mfma_f32_16x16x32_bf16(a,b,c,0,0,0)

// ---- bf16 split helpers ---------------------------------------------------
__device__ inline u32 f2bf(float x) {
    u32 u = __float_as_uint(x);
    return (u + 0x7fffu + ((u >> 16) & 1u)) >> 16;
}
__device__ inline float bf2f(u32 b) { return __uint_as_float(b << 16); }
__device__ inline void split4(float x0, float x1, float x2, float x3,
                              u32& hw0, u32& hw1, u32& lw0, u32& lw1) {
    u32 h0 = f2bf(x0), h1 = f2bf(x1), h2 = f2bf(x2), h3 = f2bf(x3);
    u32 l0 = f2bf(x0 - bf2f(h0)), l1 = f2bf(x1 - bf2f(h1));
    u32 l2 = f2bf(x2 - bf2f(h2)), l3 = f2bf(x3 - bf2f(h3));
    hw0 = h0 | (h1 << 16); hw1 = h2 | (h3 << 16);
    lw0 = l0 | (l1 << 16); lw1 = l2 | (l3 << 16);
}

// ---------------------------------------------------------------------------
// fp32 -> split bf16 hi/lo.
// ---------------------------------------------------------------------------
__global__ __launch_bounds__(256) void conv_split_kernel(
    const float* __restrict__ in, u16* __restrict__ hi, u16* __restrict__ lo)
{
    const size_t i = (size_t)blockIdx.x * 256 + threadIdx.x;
    float4 v = ((const float4*)in)[i];
    u32 hw0, hw1, lw0, lw1;
    split4(v.x, v.y, v.z, v.w, hw0, hw1, lw0, lw1);
    *(uint2*)(hi + i * 4) = make_uint2(hw0, hw1);
    *(uint2*)(lo + i * 4) = make_uint2(lw0, lw1);
}

// ---------------------------------------------------------------------------
// Split-bf16 MFMA GEMM NT core.
// ---------------------------------------------------------------------------
#define MM_CORE(Ah_, Al_, Bh_, Bl_, Kdim)                                      \
    __shared__ __align__(16) u16 sAh[128][40], sAl[128][40];                   \
    __shared__ __align__(16) u16 sBh[128][40], sBl[128][40];                   \
    const int tid = threadIdx.x;                                               \
    const int lane = tid & 63, w = tid >> 6;                                   \
    const int lc = lane & 15, lg = lane >> 4;                                  \
    const int wr = w >> 1, wc = w & 1;                                         \
    const int i0 = blockIdx.x * 128, j0 = blockIdx.y * 128;                    \
    const int srow = tid >> 1, shalf = (tid & 1) << 4;                         \
    const u16* pAh = Ah_ + (size_t)(i0 + srow) * Kdim + shalf;                 \
    const u16* pAl = Al_ + (size_t)(i0 + srow) * Kdim + shalf;                 \
    const u16* pBh = Bh_ + (size_t)(j0 + srow) * Kdim + shalf;                 \
    const u16* pBl = Bl_ + (size_t)(j0 + srow) * Kdim + shalf;                 \
    f32x4 acc[4][4];                                                           \
    _Pragma("unroll")                                                          \
    for (int rs = 0; rs < 4; ++rs)                                             \
        _Pragma("unroll")                                                      \
        for (int cs = 0; cs < 4; ++cs) acc[rs][cs] = (f32x4){0.f,0.f,0.f,0.f};\
    for (int k0 = 0; k0 < Kdim; k0 += 32) {                                    \
        short8v va0 = *(const short8v*)(pAh + k0);                             \
        short8v va1 = *(const short8v*)(pAh + k0 + 8);                         \
        short8v vb0 = *(const short8v*)(pAl + k0);                             \
        short8v vb1 = *(const short8v*)(pAl + k0 + 8);                         \
        short8v vc0 = *(const short8v*)(pBh + k0);                             \
        short8v vc1 = *(const short8v*)(pBh + k0 + 8);                         \
        short8v vd0 = *(const short8v*)(pBl + k0);                             \
        short8v vd1 = *(const short8v*)(pBl + k0 + 8);                         \
        *(short8v*)&sAh[srow][shalf]     = va0;                                \
        *(short8v*)&sAh[srow][shalf + 8] = va1;                                \
        *(short8v*)&sAl[srow][shalf]     = vb0;                                \
        *(short8v*)&sAl[srow][shalf + 8] = vb1;                                \
        *(short8v*)&sBh[srow][shalf]     = vc0;                                \
        *(short8v*)&sBh[srow][shalf + 8] = vc1;                                \
        *(short8v*)&sBl[srow][shalf]     = vd0;                                \
        *(short8v*)&sBl[srow][shalf + 8] = vd1;                                \
        __syncthreads();                                                       \
        short8v fah[4], fal[4], fbh[4], fbl[4];                                \
        _Pragma("unroll")                                                      \
        for (int rs = 0; rs < 4; ++rs) {                                       \
            fah[rs] = *(const short8v*)&sAh[wr*64 + rs*16 + lc][lg*8];         \
            fal[rs] = *(const short8v*)&sAl[wr*64 + rs*16 + lc][lg*8];         \
        }                                                                      \
        _Pragma("unroll")                                                      \
        for (int cs = 0; cs < 4; ++cs) {                                       \
            fbh[cs] = *(const short8v*)&sBh[wc*64 + cs*16 + lc][lg*8];         \
            fbl[cs] = *(const short8v*)&sBl[wc*64 + cs*16 + lc][lg*8];         \
        }                                                                      \
        _Pragma("unroll")                                                      \
        for (int rs = 0; rs < 4; ++rs)                                         \
            _Pragma("unroll")                                                  \
            for (int cs = 0; cs < 4; ++cs) {                                   \
                acc[rs][cs] = MFMA16(fah[rs], fbh[cs], acc[rs][cs]);           \
                acc[rs][cs] = MFMA16(fah[rs], fbl[cs], acc[rs][cs]);           \
                acc[rs][cs] = MFMA16(fal[rs], fbh[cs], acc[rs][cs]);           \
            }                                                                  \
        __syncthreads();                                                       \
    }

__global__ __launch_bounds__(256) void mm_qkv_kernel(
    const u16* __restrict__ Ah, const u16* __restrict__ Al,
    const u16* __restrict__ Bh, const u16* __restrict__ Bl,
    const float* __restrict__ bias,
    u16* __restrict__ qhi, u16* __restrict__ qlo,
    u16* __restrict__ khi, u16* __restrict__ klo,
    u16* __restrict__ vthi, u16* __restrict__ vtlo)
{
    MM_CORE(Ah, Al, Bh, Bl, EMB)

    const int which = j0 >> 10;
    #pragma unroll
    for (int cs = 0; cs < 4; ++cs) {
        const int j = j0 + wc*64 + cs*16 + lc;
        const float bj = bias[j];
        const int e = j & (EMB - 1);
        const int hh = e >> 6, d = e & (HD - 1);
        #pragma unroll
        for (int rs = 0; rs < 4; ++rs) {
            #pragma unroll
            for (int r = 0; r < 4; ++r) {
                const int i = i0 + wr*64 + rs*16 + lg*4 + r;
                const int b = i >> 11, t = i & (TSEQ - 1);
                float val = acc[rs][cs][r] + bj;
                if (which == 0) val *= 0.125f;
                const u32 vh = f2bf(val);
                const u32 vl = f2bf(val - bf2f(vh));
                if (which == 2) {
                    const size_t ix = ((size_t)(b * NH + hh) * HD + d) * TSEQ + t;
                    vthi[ix] = (u16)vh; vtlo[ix] = (u16)vl;
                } else {
                    const size_t ix = ((size_t)(b * NH + hh) * TSEQ + t) * HD + d;
                    if (which == 0) { qhi[ix] = (u16)vh; qlo[ix] = (u16)vl; }
                    else            { khi[ix] = (u16)vh; klo[ix] = (u16)vl; }
                }
            }
        }
    }
}

__global__ __launch_bounds__(256) void mm_out_kernel(
    const u16* __restrict__ Ah, const u16* __restrict__ Al,
    const u16* __restrict__ Bh, const u16* __restrict__ Bl,
    const float* __restrict__ bias, float* __restrict__ C)
{
    MM_CORE(Ah, Al, Bh, Bl, EMB)

    #pragma unroll
    for (int cs = 0; cs < 4; ++cs) {
        const int j = j0 + wc*64 + cs*16 + lc;
        const float bj = bias[j];
        #pragma unroll
        for (int rs = 0; rs < 4; ++rs) {
            #pragma unroll
            for (int r = 0; r < 4; ++r) {
                const int i = i0 + wr*64 + rs*16 + lg*4 + r;
                C[(size_t)i * EMB + j] = acc[rs][cs][r] + bj;
            }
        }
    }
}

// ---------------------------------------------------------------------------
// Rotary on split-bf16 k, in place.
// ---------------------------------------------------------------------------
__global__ __launch_bounds__(256) void rotary_k_kernel(
    u16* __restrict__ khi, u16* __restrict__ klo,
    const float* __restrict__ mre, const float* __restrict__ mim)
{
    const int idx = blockIdx.x * 256 + threadIdx.x;   // pair index
    const int d2 = idx & 31;
    const int t  = (idx >> 5) & (TSEQ - 1);
    const int b  = idx >> 20;
    u32 h2 = *(u32*)(khi + ((size_t)idx << 1));
    u32 l2 = *(u32*)(klo + ((size_t)idx << 1));
    float kr = bf2f(h2 & 0xffff) + bf2f(l2 & 0xffff);
    float ki = bf2f(h2 >> 16) + bf2f(l2 >> 16);
    const int mix = (b * TSEQ + t) * 32 + d2;
    const float mr = mre[mix], mi = mim[mix];
    float rr = kr * mr - ki * mi;
    float ri = kr * mi + ki * mr;
    u32 hr = f2bf(rr), hx = f2bf(ri);
    u32 lr = f2bf(rr - bf2f(hr)), lx = f2bf(ri - bf2f(hx));
    *(u32*)(khi + ((size_t)idx << 1)) = hr | (hx << 16);
    *(u32*)(klo + ((size_t)idx << 1)) = lr | (lx << 16);
}

// ---------------------------------------------------------------------------
// MFMA flash attention, split-bf16 (3-term), barrier-free.
// 128 thr = 2 waves; each wave owns 16 q-rows -> 4096 waves total (4/SIMD).
// Per kv-tile (32 keys): QK (12 MFMA) -> V prefetch -> softmax (max via 4
// shuffles, P hi/lo to per-wave LDS) -> P frags -> row-sum via MFMA(P, ones)
// (2 MFMA, replaces 16 shuffle-adds) -> PV (12 MFMA).
// ---------------------------------------------------------------------------
__global__ __launch_bounds__(128, 4) void flash_attn_kernel(
    const u16* __restrict__ qhi_, const u16* __restrict__ qlo_,
    const u16* __restrict__ khi_, const u16* __restrict__ klo_,
    const u16* __restrict__ vthi_, const u16* __restrict__ vtlo_,
    const float* __restrict__ pad,
    u16* __restrict__ ohi, u16* __restrict__ olo,
    float* __restrict__ m_out, float* __restrict__ linv_out)
{
    __shared__ __align__(16) u16 Phi[2][16*40];
    __shared__ __align__(16) u16 Plo[2][16*40];

    const int tid  = threadIdx.x;
    const int lane = tid & 63;
    const int w    = tid >> 6;
    const int bh   = blockIdx.x >> 6;                 // 0..31
    const int sub  = blockIdx.x & 63;                 // 64 q-tiles of 32
    const int b    = bh >> 4, h = bh & (NH - 1);
    const int qbase = sub * 32 + w * 16;
    const int lg = lane >> 4, lc = lane & 15;

    short8v qh[2], ql[2];
    {
        const size_t qoff = ((size_t)bh * TSEQ + qbase + lc) * HD + lg*8;
        qh[0] = *(const short8v*)(qhi_ + qoff);
        qh[1] = *(const short8v*)(qhi_ + qoff + 32);
        ql[0] = *(const short8v*)(qlo_ + qoff);
        ql[1] = *(const short8v*)(qlo_ + qoff + 32);
    }

    f32x4 O[4];
    float mst[4], lst[4];
    #pragma unroll
    for (int db = 0; db < 4; ++db) O[db] = (f32x4){0.f,0.f,0.f,0.f};
    #pragma unroll
    for (int r = 0; r < 4; ++r) { mst[r] = -1e30f; lst[r] = 0.f; }

    const short oneb = (short)0x3F80;                 // bf16 1.0
    const short8v ones = {oneb,oneb,oneb,oneb,oneb,oneb,oneb,oneb};

    u16* PHw = &Phi[w][0];
    u16* PLw = &Plo[w][0];
    const size_t kbase  = (size_t)bh * TSEQ * HD;
    const size_t vtbase = (size_t)bh * HD * TSEQ;

    for (int k0 = 0; k0 < TSEQ; k0 += 32) {
        // ---- QK^T: 12 MFMA ----
        f32x4 S[2];
        S[0] = (f32x4){0.f,0.f,0.f,0.f};
        S[1] = (f32x4){0.f,0.f,0.f,0.f};
        #pragma unroll
        for (int kb2 = 0; kb2 < 2; ++kb2) {
            #pragma unroll
            for (int s = 0; s < 2; ++s) {
                const size_t ko = kbase + (size_t)(k0 + kb2*16 + lc) * HD + s*32 + lg*8;
                short8v kh = *(const short8v*)(khi_ + ko);
                short8v kl = *(const short8v*)(klo_ + ko);
                S[kb2] = MFMA16(qh[s], kh, S[kb2]);
                S[kb2] = MFMA16(qh[s], kl, S[kb2]);
                S[kb2] = MFMA16(ql[s], kh, S[kb2]);
            }
        }

        // ---- V prefetch (latency hides under softmax) ----
        short8v vh[4], vl[4];
        #pragma unroll
        for (int db = 0; db < 4; ++db) {
            const size_t vo = vtbase + (size_t)(db*16 + lc) * TSEQ + k0 + lg*8;
            vh[db] = *(const short8v*)(vthi_ + vo);
            vl[db] = *(const short8v*)(vtlo_ + vo);
        }

        const float pv0 = pad[b * TSEQ + k0 + lc];
        const float pv1 = pad[b * TSEQ + k0 + 16 + lc];

        // ---- softmax: max (4 shuffles/row), P write, O rescale ----
        float cc_[4];
        #pragma unroll
        for (int r = 0; r < 4; ++r) {
            float s0 = S[0][r] + pv0;
            float s1 = S[1][r] + pv1;
            float t = fmaxf(s0, s1);
            t = fmaxf(t, __shfl_xor(t, 1));
            t = fmaxf(t, __shfl_xor(t, 2));
            t = fmaxf(t, __shfl_xor(t, 4));
            t = fmaxf(t, __shfl_xor(t, 8));
            const float mn = fmaxf(mst[r], t);
            cc_[r] = EXP2((mst[r] - mn) * L2E);
            mst[r] = mn;
            const float p0 = EXP2((s0 - mn) * L2E);
            const float p1 = EXP2((s1 - mn) * L2E);
            const int row = lg*4 + r;
            const u32 h0 = f2bf(p0), h1 = f2bf(p1);
            PHw[row*40 + lc]      = (u16)h0;
            PHw[row*40 + 16 + lc] = (u16)h1;
            PLw[row*40 + lc]      = (u16)f2bf(p0 - bf2f(h0));
            PLw[row*40 + 16 + lc] = (u16)f2bf(p1 - bf2f(h1));
            #pragma unroll
            for (int db = 0; db < 4; ++db) O[db][r] *= cc_[r];
        }

        // ---- P A-frags ----
        short8v pfh = *(const short8v*)(PHw + lc*40 + lg*8);
        short8v pfl = *(const short8v*)(PLw + lc*40 + lg*8);

        // ---- row sums via MFMA(P, ones): replaces 16 shuffle-adds ----
        f32x4 Ss = (f32x4){0.f,0.f,0.f,0.f};
        Ss = MFMA16(pfh, ones, Ss);
        Ss = MFMA16(pfl, ones, Ss);
        #pragma unroll
        for (int r = 0; r < 4; ++r) lst[r] = lst[r] * cc_[r] + Ss[r];

        // ---- PV: 12 MFMA ----
        #pragma unroll
        for (int db = 0; db < 4; ++db) {
            O[db] = MFMA16(pfh, vh[db], O[db]);
            O[db] = MFMA16(pfh, vl[db], O[db]);
            O[db] = MFMA16(pfl, vh[db], O[db]);
        }
    }

    // ---- epilogue: split-bf16 o + stats ----
    #pragma unroll
    for (int r = 0; r < 4; ++r) {
        const float inv = 1.f / lst[r];
        const int trow = qbase + lg*4 + r;
        const size_t obase = ((size_t)(b * TSEQ + trow)) * EMB + h * HD;
        #pragma unroll
        for (int db = 0; db < 4; ++db) {
            const float val = O[db][r] * inv;
            const u32 vhp = f2bf(val);
            ohi[obase + db*16 + lc] = (u16)vhp;
            olo[obase + db*16 + lc] = (u16)f2bf(val - bf2f(vhp));
        }
        if (lc == 0) {
            m_out[bh * TSEQ + trow] = mst[r];
            linv_out[bh * TSEQ + trow] = inv;
        }
    }
}

// ---------------------------------------------------------------------------
// a_avg via MFMA score recompute + saved stats. Barrier-free, no LDS.
// ---------------------------------------------------------------------------
__global__ __launch_bounds__(256) void attn_avg_kernel(
    const u16* __restrict__ qhi_, const u16* __restrict__ qlo_,
    const u16* __restrict__ khi_, const u16* __restrict__ klo_,
    const float* __restrict__ pad, const float* __restrict__ m_arr,
    const float* __restrict__ linv_arr, float* __restrict__ a_avg)
{
    const int tid  = threadIdx.x;
    const int lane = tid & 63;
    const int w    = tid >> 6;
    const int b  = blockIdx.z;
    const int q0 = blockIdx.y << 5;
    const int k0 = blockIdx.x << 7;
    const int lg = lane >> 4, lc = lane & 15;
    const int kw = k0 + w * 32;

    const float pv0 = pad[b * TSEQ + kw + lc];
    const float pv1 = pad[b * TSEQ + kw + 16 + lc];

    f32x4 acc[2][2];
    #pragma unroll
    for (int qs = 0; qs < 2; ++qs)
        #pragma unroll
        for (int kb2 = 0; kb2 < 2; ++kb2) acc[qs][kb2] = (f32x4){0.f,0.f,0.f,0.f};

    for (int h = 0; h < NH; ++h) {
        const size_t hb = (size_t)(b * NH + h) * TSEQ;
        short8v qh[2][2], ql[2][2];
        #pragma unroll
        for (int qs = 0; qs < 2; ++qs) {
            const size_t qoff = (hb + q0 + qs*16 + lc) * HD + lg*8;
            #pragma unroll
            for (int s = 0; s < 2; ++s) {
                qh[qs][s] = *(const short8v*)(qhi_ + qoff + s*32);
                ql[qs][s] = *(const short8v*)(qlo_ + qoff + s*32);
            }
        }
        f32x4 S[2][2];
        #pragma unroll
        for (int qs = 0; qs < 2; ++qs)
            #pragma unroll
            for (int kb2 = 0; kb2 < 2; ++kb2) S[qs][kb2] = (f32x4){0.f,0.f,0.f,0.f};
        #pragma unroll
        for (int kb2 = 0; kb2 < 2; ++kb2) {
            #pragma unroll
            for (int s = 0; s < 2; ++s) {
                const size_t ko = (hb + kw + kb2*16 + lc) * HD + s*32 + lg*8;
                short8v kh = *(const short8v*)(khi_ + ko);
                short8v kl = *(const short8v*)(klo_ + ko);
                #pragma unroll
                for (int qs = 0; qs < 2; ++qs) {
                    S[qs][kb2] = MFMA16(qh[qs][s], kh, S[qs][kb2]);
                    S[qs][kb2] = MFMA16(qh[qs][s], kl, S[qs][kb2]);
                    S[qs][kb2] = MFMA16(ql[qs][s], kh, S[qs][kb2]);
                }
            }
        }
        #pragma unroll
        for (int qs = 0; qs < 2; ++qs) {
            #pragma unroll
            for (int r = 0; r < 4; ++r) {
                const size_t rix = hb + q0 + qs*16 + lg*4 + r;
                const float mh = m_arr[rix];
                const float li = linv_arr[rix];
                acc[qs][0][r] += EXP2((S[qs][0][r] + pv0 - mh) * L2E) * li;
                acc[qs][1][r] += EXP2((S[qs][1][r] + pv1 - mh) * L2E) * li;
            }
        }
    }

    const float invH = 1.0f / (float)NH;
    #pragma unroll
    for (int qs = 0; qs < 2; ++qs) {
        #pragma unroll
        for (int r = 0; r < 4; ++r) {
            const int row = q0 + qs*16 + lg*4 + r;
            #pragma unroll
            for (int kb2 = 0; kb2 < 2; ++kb2)
                a_avg[((size_t)b * TSEQ + row) * TSEQ + kw + kb2*16 + lc] =
                    acc[qs][kb2][r] * invH;
        }
    }
}

// ---------------------------------------------------------------------------
extern "C" void kernel_launch(void* const* d_in, const int* in_sizes, int n_in,
                              void* d_out, int out_size, void* d_ws, size_t ws_size,
                              hipStream_t stream)
{
    const float* x    = (const float*)d_in[0];
    const float* mre  = (const float*)d_in[1];
    const float* mim  = (const float*)d_in[2];
    const float* pad  = (const float*)d_in[3];
    const float* qkvw = (const float*)d_in[4];
    const float* qkvb = (const float*)d_in[5];
    const float* ow   = (const float*)d_in[6];
    const float* ob   = (const float*)d_in[7];

    float* out_o = (float*)d_out;                    // [B,T,E]
    float* out_a = out_o + (size_t)NB * TSEQ * EMB;  // [B,T,T]

    // o split-bf16 borrows the a_avg output region; consumed by mm_out
    // before attn_avg overwrites it (stream-ordered).
    u16* ohi = (u16*)out_a;
    u16* olo = ohi + (size_t)NB * TSEQ * EMB;

    // ws (u16 units): q|k|v splits (6xSZ) + stats + x|w|ow splits  (~84.5 MB)
    const size_t SZ = (size_t)NB * NH * TSEQ * HD;   // 4194304
    u16* qhi  = (u16*)d_ws;
    u16* qlo  = qhi  + SZ;
    u16* khi  = qlo  + SZ;
    u16* klo  = khi  + SZ;
    u16* vthi = klo  + SZ;
    u16* vtlo = vthi + SZ;
    float* marr = (float*)(vtlo + SZ);
    float* linv = marr + (size_t)NB * NH * TSEQ;
    u16* xhi  = (u16*)(linv + (size_t)NB * NH * TSEQ);
    u16* xlo  = xhi + SZ;                            // x: 4096x1024
    u16* whi  = xlo + SZ;                            // qkv_w: 3072x1024
    u16* wlo  = whi + (size_t)3 * EMB * EMB;
    u16* owhi = wlo + (size_t)3 * EMB * EMB;         // o_w: 1024x1024
    u16* owlo = owhi + (size_t)EMB * EMB;

    // 0) split inputs to bf16 hi/lo
    conv_split_kernel<<<4096, 256, 0, stream>>>(x, xhi, xlo);
    conv_split_kernel<<<3072, 256, 0, stream>>>(qkvw, whi, wlo);
    conv_split_kernel<<<1024, 256, 0, stream>>>(ow, owhi, owlo);

    // 1) QKV projection (MFMA) -> split q/k (BHTd) + v transposed (BHdT)
    mm_qkv_kernel<<<dim3(32, 24), 256, 0, stream>>>(
        xhi, xlo, whi, wlo, qkvb, qhi, qlo, khi, klo, vthi, vtlo);

    // 2) rotary on k (in place, split-bf16)
    rotary_k_kernel<<<8192, 256, 0, stream>>>(khi, klo, mre, mim);

    // 3) MFMA flash attention -> o split-bf16 + stats (4096 waves)
    flash_attn_kernel<<<2048, 128, 0, stream>>>(
        qhi, qlo, khi, klo, vthi, vtlo, pad, ohi, olo, marr, linv);

    // 4) output projection (MFMA, consumes o-split)
    mm_out_kernel<<<dim3(32, 8), 256, 0, stream>>>(
        ohi, olo, owhi, owlo, ob, out_o);

    // 5) head-averaged probs -> a_avg (overwrites scratch region)
    attn_avg_kernel<<<dim3(16, 64, 2), 256, 0, stream>>>(
        qhi, qlo, khi, klo, pad, marr, linv, out_a);
}

// Round 11
// 731.756 us; speedup vs baseline: 1.2963x; 1.2963x over previous
//
#include <hip/hip_runtime.h>
#include <math.h>

#define TSEQ 2048
#define EMB  1024
#define NH   16
#define HD   64
#define NB   2
#define L2E  1.4426950408889634f

#if defined(__has_builtin)
#if __has_builtin(__builtin_amdgcn_exp2f)
#define EXP2(x) __builtin_amdgcn_exp2f(x)
#else
#define EXP2(x) exp2f(x)
#endif
#else
#define EXP2(x) exp2f(x)
#endif

typedef unsigned short u16;
typedef unsigned int   u32;
typedef __attribute__((ext_vector_type(8))) short short8v;  // 8 bf16
typedef __attribute__((ext_vector_type(4))) float f32x4;

#define MFMA16(a,b,c) __builtin_amdgcn_mfma_f32_16x16x32_bf16(a,b,c,0,0,0)

// ---- bf16 split helpers ---------------------------------------------------
__device__ inline u32 f2bf(float x) {
    u32 u = __float_as_uint(x);
    return (u + 0x7fffu + ((u >> 16) & 1u)) >> 16;
}
__device__ inline float bf2f(u32 b) { return __uint_as_float(b << 16); }
__device__ inline void split4(float x0, float x1, float x2, float x3,
                              u32& hw0, u32& hw1, u32& lw0, u32& lw1) {
    u32 h0 = f2bf(x0), h1 = f2bf(x1), h2 = f2bf(x2), h3 = f2bf(x3);
    u32 l0 = f2bf(x0 - bf2f(h0)), l1 = f2bf(x1 - bf2f(h1));
    u32 l2 = f2bf(x2 - bf2f(h2)), l3 = f2bf(x3 - bf2f(h3));
    hw0 = h0 | (h1 << 16); hw1 = h2 | (h3 << 16);
    lw0 = l0 | (l1 << 16); lw1 = l2 | (l3 << 16);
}

// ---------------------------------------------------------------------------
// fp32 -> split bf16 hi/lo.
// ---------------------------------------------------------------------------
__global__ __launch_bounds__(256) void conv_split_kernel(
    const float* __restrict__ in, u16* __restrict__ hi, u16* __restrict__ lo)
{
    const size_t i = (size_t)blockIdx.x * 256 + threadIdx.x;
    float4 v = ((const float4*)in)[i];
    u32 hw0, hw1, lw0, lw1;
    split4(v.x, v.y, v.z, v.w, hw0, hw1, lw0, lw1);
    *(uint2*)(hi + i * 4) = make_uint2(hw0, hw1);
    *(uint2*)(lo + i * 4) = make_uint2(lw0, lw1);
}

// ---------------------------------------------------------------------------
// Split-bf16 MFMA GEMM NT core.
// ---------------------------------------------------------------------------
#define MM_CORE(Ah_, Al_, Bh_, Bl_, Kdim)                                      \
    __shared__ __align__(16) u16 sAh[128][40], sAl[128][40];                   \
    __shared__ __align__(16) u16 sBh[128][40], sBl[128][40];                   \
    const int tid = threadIdx.x;                                               \
    const int lane = tid & 63, w = tid >> 6;                                   \
    const int lc = lane & 15, lg = lane >> 4;                                  \
    const int wr = w >> 1, wc = w & 1;                                         \
    const int i0 = blockIdx.x * 128, j0 = blockIdx.y * 128;                    \
    const int srow = tid >> 1, shalf = (tid & 1) << 4;                         \
    const u16* pAh = Ah_ + (size_t)(i0 + srow) * Kdim + shalf;                 \
    const u16* pAl = Al_ + (size_t)(i0 + srow) * Kdim + shalf;                 \
    const u16* pBh = Bh_ + (size_t)(j0 + srow) * Kdim + shalf;                 \
    const u16* pBl = Bl_ + (size_t)(j0 + srow) * Kdim + shalf;                 \
    f32x4 acc[4][4];                                                           \
    _Pragma("unroll")                                                          \
    for (int rs = 0; rs < 4; ++rs)                                             \
        _Pragma("unroll")                                                      \
        for (int cs = 0; cs < 4; ++cs) acc[rs][cs] = (f32x4){0.f,0.f,0.f,0.f};\
    for (int k0 = 0; k0 < Kdim; k0 += 32) {                                    \
        short8v va0 = *(const short8v*)(pAh + k0);                             \
        short8v va1 = *(const short8v*)(pAh + k0 + 8);                         \
        short8v vb0 = *(const short8v*)(pAl + k0);                             \
        short8v vb1 = *(const short8v*)(pAl + k0 + 8);                         \
        short8v vc0 = *(const short8v*)(pBh + k0);                             \
        short8v vc1 = *(const short8v*)(pBh + k0 + 8);                         \
        short8v vd0 = *(const short8v*)(pBl + k0);                             \
        short8v vd1 = *(const short8v*)(pBl + k0 + 8);                         \
        *(short8v*)&sAh[srow][shalf]     = va0;                                \
        *(short8v*)&sAh[srow][shalf + 8] = va1;                                \
        *(short8v*)&sAl[srow][shalf]     = vb0;                                \
        *(short8v*)&sAl[srow][shalf + 8] = vb1;                                \
        *(short8v*)&sBh[srow][shalf]     = vc0;                                \
        *(short8v*)&sBh[srow][shalf + 8] = vc1;                                \
        *(short8v*)&sBl[srow][shalf]     = vd0;                                \
        *(short8v*)&sBl[srow][shalf + 8] = vd1;                                \
        __syncthreads();                                                       \
        short8v fah[4], fal[4], fbh[4], fbl[4];                                \
        _Pragma("unroll")                                                      \
        for (int rs = 0; rs < 4; ++rs) {                                       \
            fah[rs] = *(const short8v*)&sAh[wr*64 + rs*16 + lc][lg*8];         \
            fal[rs] = *(const short8v*)&sAl[wr*64 + rs*16 + lc][lg*8];         \
        }                                                                      \
        _Pragma("unroll")                                                      \
        for (int cs = 0; cs < 4; ++cs) {                                       \
            fbh[cs] = *(const short8v*)&sBh[wc*64 + cs*16 + lc][lg*8];         \
            fbl[cs] = *(const short8v*)&sBl[wc*64 + cs*16 + lc][lg*8];         \
        }                                                                      \
        _Pragma("unroll")                                                      \
        for (int rs = 0; rs < 4; ++rs)                                         \
            _Pragma("unroll")                                                  \
            for (int cs = 0; cs < 4; ++cs) {                                   \
                acc[rs][cs] = MFMA16(fah[rs], fbh[cs], acc[rs][cs]);           \
                acc[rs][cs] = MFMA16(fah[rs], fbl[cs], acc[rs][cs]);           \
                acc[rs][cs] = MFMA16(fal[rs], fbh[cs], acc[rs][cs]);           \
            }                                                                  \
        __syncthreads();                                                       \
    }

__global__ __launch_bounds__(256) void mm_qkv_kernel(
    const u16* __restrict__ Ah, const u16* __restrict__ Al,
    const u16* __restrict__ Bh, const u16* __restrict__ Bl,
    const float* __restrict__ bias,
    u16* __restrict__ qhi, u16* __restrict__ qlo,
    u16* __restrict__ khi, u16* __restrict__ klo,
    u16* __restrict__ vthi, u16* __restrict__ vtlo)
{
    MM_CORE(Ah, Al, Bh, Bl, EMB)

    const int which = j0 >> 10;
    #pragma unroll
    for (int cs = 0; cs < 4; ++cs) {
        const int j = j0 + wc*64 + cs*16 + lc;
        const float bj = bias[j];
        const int e = j & (EMB - 1);
        const int hh = e >> 6, d = e & (HD - 1);
        #pragma unroll
        for (int rs = 0; rs < 4; ++rs) {
            #pragma unroll
            for (int r = 0; r < 4; ++r) {
                const int i = i0 + wr*64 + rs*16 + lg*4 + r;
                const int b = i >> 11, t = i & (TSEQ - 1);
                float val = acc[rs][cs][r] + bj;
                if (which == 0) val *= 0.125f;
                const u32 vh = f2bf(val);
                const u32 vl = f2bf(val - bf2f(vh));
                if (which == 2) {
                    const size_t ix = ((size_t)(b * NH + hh) * HD + d) * TSEQ + t;
                    vthi[ix] = (u16)vh; vtlo[ix] = (u16)vl;
                } else {
                    const size_t ix = ((size_t)(b * NH + hh) * TSEQ + t) * HD + d;
                    if (which == 0) { qhi[ix] = (u16)vh; qlo[ix] = (u16)vl; }
                    else            { khi[ix] = (u16)vh; klo[ix] = (u16)vl; }
                }
            }
        }
    }
}

__global__ __launch_bounds__(256) void mm_out_kernel(
    const u16* __restrict__ Ah, const u16* __restrict__ Al,
    const u16* __restrict__ Bh, const u16* __restrict__ Bl,
    const float* __restrict__ bias, float* __restrict__ C)
{
    MM_CORE(Ah, Al, Bh, Bl, EMB)

    #pragma unroll
    for (int cs = 0; cs < 4; ++cs) {
        const int j = j0 + wc*64 + cs*16 + lc;
        const float bj = bias[j];
        #pragma unroll
        for (int rs = 0; rs < 4; ++rs) {
            #pragma unroll
            for (int r = 0; r < 4; ++r) {
                const int i = i0 + wr*64 + rs*16 + lg*4 + r;
                C[(size_t)i * EMB + j] = acc[rs][cs][r] + bj;
            }
        }
    }
}

// ---------------------------------------------------------------------------
// Rotary on split-bf16 k, in place.
// ---------------------------------------------------------------------------
__global__ __launch_bounds__(256) void rotary_k_kernel(
    u16* __restrict__ khi, u16* __restrict__ klo,
    const float* __restrict__ mre, const float* __restrict__ mim)
{
    const int idx = blockIdx.x * 256 + threadIdx.x;   // pair index
    const int d2 = idx & 31;
    const int t  = (idx >> 5) & (TSEQ - 1);
    const int b  = idx >> 20;
    u32 h2 = *(u32*)(khi + ((size_t)idx << 1));
    u32 l2 = *(u32*)(klo + ((size_t)idx << 1));
    float kr = bf2f(h2 & 0xffff) + bf2f(l2 & 0xffff);
    float ki = bf2f(h2 >> 16) + bf2f(l2 >> 16);
    const int mix = (b * TSEQ + t) * 32 + d2;
    const float mr = mre[mix], mi = mim[mix];
    float rr = kr * mr - ki * mi;
    float ri = kr * mi + ki * mr;
    u32 hr = f2bf(rr), hx = f2bf(ri);
    u32 lr = f2bf(rr - bf2f(hr)), lx = f2bf(ri - bf2f(hx));
    *(u32*)(khi + ((size_t)idx << 1)) = hr | (hx << 16);
    *(u32*)(klo + ((size_t)idx << 1)) = lr | (lx << 16);
}

// ---------------------------------------------------------------------------
// MFMA flash attention, split-bf16 (3-term), barrier-free.
// Geometry: 2 waves/block x 32 q-rows (round-8 measured-best: 50 MFMA per
// 16 global loads). Grid 1024 blocks, 1-D, XCD-SWIZZLED: xcd = bid&7 owns
// bh group [xcd*4, xcd*4+4) -> per-XCD K/V working set 4 MB = L2 size, so
// K/V stream from HBM once per XCD instead of ~4x (round-10 FETCH=139MB).
// Keeps round-10 micro-opts: V prefetch above softmax, row-sum via
// MFMA(P, ones).
// ---------------------------------------------------------------------------
__global__ __launch_bounds__(128) void flash_attn_kernel(
    const u16* __restrict__ qhi_, const u16* __restrict__ qlo_,
    const u16* __restrict__ khi_, const u16* __restrict__ klo_,
    const u16* __restrict__ vthi_, const u16* __restrict__ vtlo_,
    const float* __restrict__ pad,
    u16* __restrict__ ohi, u16* __restrict__ olo,
    float* __restrict__ m_out, float* __restrict__ linv_out)
{
    __shared__ __align__(16) u16 Phi[2][32*40];
    __shared__ __align__(16) u16 Plo[2][32*40];

    const int tid  = threadIdx.x;
    const int lane = tid & 63;
    const int w    = tid >> 6;
    const int bid  = blockIdx.x;
    const int xcd  = bid & 7;
    const int local= bid >> 3;                        // 0..127
    const int bh   = xcd * 4 + (local >> 5);          // 4 bh per XCD
    const int sub  = local & 31;                      // 32 q-tiles of 64
    const int b    = bh >> 4, h = bh & (NH - 1);
    const int qbase = sub * 64 + w * 32;
    const int lg = lane >> 4, lc = lane & 15;

    short8v qh[2][2], ql[2][2];
    #pragma unroll
    for (int qs = 0; qs < 2; ++qs) {
        const size_t qoff = ((size_t)bh * TSEQ + qbase + qs*16 + lc) * HD + lg*8;
        #pragma unroll
        for (int s = 0; s < 2; ++s) {
            qh[qs][s] = *(const short8v*)(qhi_ + qoff + s*32);
            ql[qs][s] = *(const short8v*)(qlo_ + qoff + s*32);
        }
    }

    f32x4 O[2][4];
    float mst[2][4], lst[2][4];
    #pragma unroll
    for (int qs = 0; qs < 2; ++qs) {
        #pragma unroll
        for (int db = 0; db < 4; ++db) O[qs][db] = (f32x4){0.f,0.f,0.f,0.f};
        #pragma unroll
        for (int r = 0; r < 4; ++r) { mst[qs][r] = -1e30f; lst[qs][r] = 0.f; }
    }

    const short oneb = (short)0x3F80;                 // bf16 1.0
    const short8v ones = {oneb,oneb,oneb,oneb,oneb,oneb,oneb,oneb};

    u16* PHw = &Phi[w][0];
    u16* PLw = &Plo[w][0];
    const size_t kbase  = (size_t)bh * TSEQ * HD;
    const size_t vtbase = (size_t)bh * HD * TSEQ;

    for (int k0 = 0; k0 < TSEQ; k0 += 32) {
        // ---- QK^T: 24 MFMA ----
        f32x4 S[2][2];
        #pragma unroll
        for (int qs = 0; qs < 2; ++qs)
            #pragma unroll
            for (int kb2 = 0; kb2 < 2; ++kb2) S[qs][kb2] = (f32x4){0.f,0.f,0.f,0.f};
        #pragma unroll
        for (int kb2 = 0; kb2 < 2; ++kb2) {
            #pragma unroll
            for (int s = 0; s < 2; ++s) {
                const size_t ko = kbase + (size_t)(k0 + kb2*16 + lc) * HD + s*32 + lg*8;
                short8v kh = *(const short8v*)(khi_ + ko);
                short8v kl = *(const short8v*)(klo_ + ko);
                #pragma unroll
                for (int qs = 0; qs < 2; ++qs) {
                    S[qs][kb2] = MFMA16(qh[qs][s], kh, S[qs][kb2]);
                    S[qs][kb2] = MFMA16(qh[qs][s], kl, S[qs][kb2]);
                    S[qs][kb2] = MFMA16(ql[qs][s], kh, S[qs][kb2]);
                }
            }
        }

        // ---- V prefetch (latency hides under softmax) ----
        short8v vh[4], vl[4];
        #pragma unroll
        for (int db = 0; db < 4; ++db) {
            const size_t vo = vtbase + (size_t)(db*16 + lc) * TSEQ + k0 + lg*8;
            vh[db] = *(const short8v*)(vthi_ + vo);
            vl[db] = *(const short8v*)(vtlo_ + vo);
        }

        const float pv0 = pad[b * TSEQ + k0 + lc];
        const float pv1 = pad[b * TSEQ + k0 + 16 + lc];

        // ---- softmax: max (4 shuffles/row), P write, O rescale ----
        float cc_[2][4];
        #pragma unroll
        for (int qs = 0; qs < 2; ++qs) {
            #pragma unroll
            for (int r = 0; r < 4; ++r) {
                float s0 = S[qs][0][r] + pv0;
                float s1 = S[qs][1][r] + pv1;
                float t = fmaxf(s0, s1);
                t = fmaxf(t, __shfl_xor(t, 1));
                t = fmaxf(t, __shfl_xor(t, 2));
                t = fmaxf(t, __shfl_xor(t, 4));
                t = fmaxf(t, __shfl_xor(t, 8));
                const float mn = fmaxf(mst[qs][r], t);
                cc_[qs][r] = EXP2((mst[qs][r] - mn) * L2E);
                mst[qs][r] = mn;
                const float p0 = EXP2((s0 - mn) * L2E);
                const float p1 = EXP2((s1 - mn) * L2E);
                const int row = qs*16 + lg*4 + r;
                const u32 h0 = f2bf(p0), h1 = f2bf(p1);
                PHw[row*40 + lc]      = (u16)h0;
                PHw[row*40 + 16 + lc] = (u16)h1;
                PLw[row*40 + lc]      = (u16)f2bf(p0 - bf2f(h0));
                PLw[row*40 + 16 + lc] = (u16)f2bf(p1 - bf2f(h1));
                #pragma unroll
                for (int db = 0; db < 4; ++db) O[qs][db][r] *= cc_[qs][r];
            }
        }

        // ---- P A-frags ----
        short8v pfh[2], pfl[2];
        #pragma unroll
        for (int qs = 0; qs < 2; ++qs) {
            pfh[qs] = *(const short8v*)(PHw + (qs*16 + lc)*40 + lg*8);
            pfl[qs] = *(const short8v*)(PLw + (qs*16 + lc)*40 + lg*8);
        }

        // ---- row sums via MFMA(P, ones) ----
        #pragma unroll
        for (int qs = 0; qs < 2; ++qs) {
            f32x4 Ss = (f32x4){0.f,0.f,0.f,0.f};
            Ss = MFMA16(pfh[qs], ones, Ss);
            Ss = MFMA16(pfl[qs], ones, Ss);
            #pragma unroll
            for (int r = 0; r < 4; ++r) lst[qs][r] = lst[qs][r] * cc_[qs][r] + Ss[r];
        }

        // ---- PV: 24 MFMA ----
        #pragma unroll
        for (int db = 0; db < 4; ++db) {
            #pragma unroll
            for (int qs = 0; qs < 2; ++qs) {
                O[qs][db] = MFMA16(pfh[qs], vh[db], O[qs][db]);
                O[qs][db] = MFMA16(pfh[qs], vl[db], O[qs][db]);
                O[qs][db] = MFMA16(pfl[qs], vh[db], O[qs][db]);
            }
        }
    }

    // ---- epilogue: split-bf16 o + stats ----
    #pragma unroll
    for (int qs = 0; qs < 2; ++qs) {
        #pragma unroll
        for (int r = 0; r < 4; ++r) {
            const float inv = 1.f / lst[qs][r];
            const int trow = qbase + qs*16 + lg*4 + r;
            const size_t obase = ((size_t)(b * TSEQ + trow)) * EMB + h * HD;
            #pragma unroll
            for (int db = 0; db < 4; ++db) {
                const float val = O[qs][db][r] * inv;
                const u32 vhp = f2bf(val);
                ohi[obase + db*16 + lc] = (u16)vhp;
                olo[obase + db*16 + lc] = (u16)f2bf(val - bf2f(vhp));
            }
            if (lc == 0) {
                m_out[bh * TSEQ + trow] = mst[qs][r];
                linv_out[bh * TSEQ + trow] = inv;
            }
        }
    }
}

// ---------------------------------------------------------------------------
// a_avg via MFMA score recompute + saved stats. Barrier-free, no LDS.
// 1-D grid 2048, XCD-SWIZZLED: xcd owns 4 (b,k0)-pairs; the 64 q-blocks of
// one pair share that pair's 512KB K slice in the XCD's L2.
// ---------------------------------------------------------------------------
__global__ __launch_bounds__(256) void attn_avg_kernel(
    const u16* __restrict__ qhi_, const u16* __restrict__ qlo_,
    const u16* __restrict__ khi_, const u16* __restrict__ klo_,
    const float* __restrict__ pad, const float* __restrict__ m_arr,
    const float* __restrict__ linv_arr, float* __restrict__ a_avg)
{
    const int tid  = threadIdx.x;
    const int lane = tid & 63;
    const int w    = tid >> 6;
    const int bid  = blockIdx.x;
    const int xcd  = bid & 7;
    const int local= bid >> 3;            // 0..255
    const int pair = xcd * 4 + (local >> 6);   // 0..31 = (b, k-block)
    const int b  = pair >> 4;
    const int k0 = (pair & 15) << 7;
    const int q0 = (local & 63) << 5;
    const int lg = lane >> 4, lc = lane & 15;
    const int kw = k0 + w * 32;

    const float pv0 = pad[b * TSEQ + kw + lc];
    const float pv1 = pad[b * TSEQ + kw + 16 + lc];

    f32x4 acc[2][2];
    #pragma unroll
    for (int qs = 0; qs < 2; ++qs)
        #pragma unroll
        for (int kb2 = 0; kb2 < 2; ++kb2) acc[qs][kb2] = (f32x4){0.f,0.f,0.f,0.f};

    for (int h = 0; h < NH; ++h) {
        const size_t hb = (size_t)(b * NH + h) * TSEQ;
        short8v qh[2][2], ql[2][2];
        #pragma unroll
        for (int qs = 0; qs < 2; ++qs) {
            const size_t qoff = (hb + q0 + qs*16 + lc) * HD + lg*8;
            #pragma unroll
            for (int s = 0; s < 2; ++s) {
                qh[qs][s] = *(const short8v*)(qhi_ + qoff + s*32);
                ql[qs][s] = *(const short8v*)(qlo_ + qoff + s*32);
            }
        }
        f32x4 S[2][2];
        #pragma unroll
        for (int qs = 0; qs < 2; ++qs)
            #pragma unroll
            for (int kb2 = 0; kb2 < 2; ++kb2) S[qs][kb2] = (f32x4){0.f,0.f,0.f,0.f};
        #pragma unroll
        for (int kb2 = 0; kb2 < 2; ++kb2) {
            #pragma unroll
            for (int s = 0; s < 2; ++s) {
                const size_t ko = (hb + kw + kb2*16 + lc) * HD + s*32 + lg*8;
                short8v kh = *(const short8v*)(khi_ + ko);
                short8v kl = *(const short8v*)(klo_ + ko);
                #pragma unroll
                for (int qs = 0; qs < 2; ++qs) {
                    S[qs][kb2] = MFMA16(qh[qs][s], kh, S[qs][kb2]);
                    S[qs][kb2] = MFMA16(qh[qs][s], kl, S[qs][kb2]);
                    S[qs][kb2] = MFMA16(ql[qs][s], kh, S[qs][kb2]);
                }
            }
        }
        #pragma unroll
        for (int qs = 0; qs < 2; ++qs) {
            #pragma unroll
            for (int r = 0; r < 4; ++r) {
                const size_t rix = hb + q0 + qs*16 + lg*4 + r;
                const float mh = m_arr[rix];
                const float li = linv_arr[rix];
                acc[qs][0][r] += EXP2((S[qs][0][r] + pv0 - mh) * L2E) * li;
                acc[qs][1][r] += EXP2((S[qs][1][r] + pv1 - mh) * L2E) * li;
            }
        }
    }

    const float invH = 1.0f / (float)NH;
    #pragma unroll
    for (int qs = 0; qs < 2; ++qs) {
        #pragma unroll
        for (int r = 0; r < 4; ++r) {
            const int row = q0 + qs*16 + lg*4 + r;
            #pragma unroll
            for (int kb2 = 0; kb2 < 2; ++kb2)
                a_avg[((size_t)b * TSEQ + row) * TSEQ + kw + kb2*16 + lc] =
                    acc[qs][kb2][r] * invH;
        }
    }
}

// ---------------------------------------------------------------------------
extern "C" void kernel_launch(void* const* d_in, const int* in_sizes, int n_in,
                              void* d_out, int out_size, void* d_ws, size_t ws_size,
                              hipStream_t stream)
{
    const float* x    = (const float*)d_in[0];
    const float* mre  = (const float*)d_in[1];
    const float* mim  = (const float*)d_in[2];
    const float* pad  = (const float*)d_in[3];
    const float* qkvw = (const float*)d_in[4];
    const float* qkvb = (const float*)d_in[5];
    const float* ow   = (const float*)d_in[6];
    const float* ob   = (const float*)d_in[7];

    float* out_o = (float*)d_out;                    // [B,T,E]
    float* out_a = out_o + (size_t)NB * TSEQ * EMB;  // [B,T,T]

    // o split-bf16 borrows the a_avg output region; consumed by mm_out
    // before attn_avg overwrites it (stream-ordered).
    u16* ohi = (u16*)out_a;
    u16* olo = ohi + (size_t)NB * TSEQ * EMB;

    // ws (u16 units): q|k|v splits (6xSZ) + stats + x|w|ow splits  (~84.5 MB)
    const size_t SZ = (size_t)NB * NH * TSEQ * HD;   // 4194304
    u16* qhi  = (u16*)d_ws;
    u16* qlo  = qhi  + SZ;
    u16* khi  = qlo  + SZ;
    u16* klo  = khi  + SZ;
    u16* vthi = klo  + SZ;
    u16* vtlo = vthi + SZ;
    float* marr = (float*)(vtlo + SZ);
    float* linv = marr + (size_t)NB * NH * TSEQ;
    u16* xhi  = (u16*)(linv + (size_t)NB * NH * TSEQ);
    u16* xlo  = xhi + SZ;                            // x: 4096x1024
    u16* whi  = xlo + SZ;                            // qkv_w: 3072x1024
    u16* wlo  = whi + (size_t)3 * EMB * EMB;
    u16* owhi = wlo + (size_t)3 * EMB * EMB;         // o_w: 1024x1024
    u16* owlo = owhi + (size_t)EMB * EMB;

    // 0) split inputs to bf16 hi/lo
    conv_split_kernel<<<4096, 256, 0, stream>>>(x, xhi, xlo);
    conv_split_kernel<<<3072, 256, 0, stream>>>(qkvw, whi, wlo);
    conv_split_kernel<<<1024, 256, 0, stream>>>(ow, owhi, owlo);

    // 1) QKV projection (MFMA) -> split q/k (BHTd) + v transposed (BHdT)
    mm_qkv_kernel<<<dim3(32, 24), 256, 0, stream>>>(
        xhi, xlo, whi, wlo, qkvb, qhi, qlo, khi, klo, vthi, vtlo);

    // 2) rotary on k (in place, split-bf16)
    rotary_k_kernel<<<8192, 256, 0, stream>>>(khi, klo, mre, mim);

    // 3) MFMA flash attention -> o split-bf16 + stats (XCD-swizzled)
    flash_attn_kernel<<<1024, 128, 0, stream>>>(
        qhi, qlo, khi, klo, vthi, vtlo, pad, ohi, olo, marr, linv);

    // 4) output projection (MFMA, consumes o-split)
    mm_out_kernel<<<dim3(32, 8), 256, 0, stream>>>(
        ohi, olo, owhi, owlo, ob, out_o);

    // 5) head-averaged probs -> a_avg (XCD-swizzled)
    attn_avg_kernel<<<2048, 256, 0, stream>>>(
        qhi, qlo, khi, klo, pad, marr, linv, out_a);
}